// Round 1
// baseline (284.372 us; speedup 1.0000x reference)
//
#include <hip/hip_runtime.h>
#include <hip/hip_bf16.h>

typedef __bf16 bf16_t;
typedef __bf16 bf16x8 __attribute__((ext_vector_type(8)));
typedef float f32x4 __attribute__((ext_vector_type(4)));

#define IN_DIM 21
#define HID 512
#define OUT_DIM 21
#define M_TILE 64
#define LSTRIDE 520   // 512 + 8 bf16 pad -> row stride 1040 B = 65 * 16 B (conflict-friendly, 16B-aligned)
#define THREADS 512

// ---- prep: convert weights fp32 -> bf16 into workspace (padded layouts) ----
// W2bf: [512][512]  W1bf: [512][32] (k 21..31 = 0)  W3bf: [32][512] (rows 21..31 = 0)
__global__ void prep_kernel(const float* __restrict__ W1, const float* __restrict__ W2,
                            const float* __restrict__ W3,
                            bf16_t* __restrict__ W1bf, bf16_t* __restrict__ W2bf,
                            bf16_t* __restrict__ W3bf) {
    int i = blockIdx.x * blockDim.x + threadIdx.x;
    int stride = gridDim.x * blockDim.x;
    const int NW2 = HID * HID;           // 262144
    const int NW1 = HID * 32;            // 16384
    const int NW3 = 32 * HID;            // 16384
    for (; i < NW2 + NW1 + NW3; i += stride) {
        if (i < NW2) {
            W2bf[i] = (bf16_t)W2[i];
        } else if (i < NW2 + NW1) {
            int j = i - NW2;
            int r = j >> 5, k = j & 31;
            W1bf[j] = (k < IN_DIM) ? (bf16_t)W1[r * IN_DIM + k] : (bf16_t)0.0f;
        } else {
            int j = i - NW2 - NW1;
            int r = j >> 9, k = j & 511;
            W3bf[j] = (r < OUT_DIM) ? (bf16_t)W3[r * HID + k] : (bf16_t)0.0f;
        }
    }
}

// ---- fused MLP + loss ----
__global__ __launch_bounds__(THREADS, 1)
void fused_kernel(const float* __restrict__ V, const float* __restrict__ gt,
                  const float* __restrict__ b1, const float* __restrict__ b2,
                  const float* __restrict__ b3,
                  const bf16_t* __restrict__ W1bf, const bf16_t* __restrict__ W2bf,
                  const bf16_t* __restrict__ W3bf, float* __restrict__ accum) {
    __shared__ __align__(16) bf16_t vlds[M_TILE][32];
    __shared__ __align__(16) bf16_t h1[M_TILE][LSTRIDE];
    __shared__ __align__(16) bf16_t h2[M_TILE][LSTRIDE];
    __shared__ float redbuf[8];

    const int tid  = threadIdx.x;
    const int wave = tid >> 6;
    const int lane = tid & 63;
    const int quad = lane >> 4;
    const int l16  = lane & 15;
    const long row0 = (long)blockIdx.x * M_TILE;

    // phase 0: velocities tile -> LDS bf16, k padded to 32 with zeros
    for (int idx = tid; idx < M_TILE * 32; idx += THREADS) {
        int r = idx >> 5, c = idx & 31;
        float v = (c < IN_DIM) ? V[(row0 + r) * IN_DIM + c] : 0.0f;
        vlds[r][c] = (bf16_t)v;
    }
    __syncthreads();

    // phase 1: h1 = relu(V @ W1^T + b1). Each wave covers n in [wave*64, wave*64+64).
    {
        bf16x8 a[4];
        #pragma unroll
        for (int mt = 0; mt < 4; ++mt)
            a[mt] = *reinterpret_cast<const bf16x8*>(&vlds[mt * 16 + l16][quad * 8]);
        #pragma unroll
        for (int nt = 0; nt < 4; ++nt) {
            int n = wave * 64 + nt * 16 + l16;
            bf16x8 b = *reinterpret_cast<const bf16x8*>(W1bf + n * 32 + quad * 8);
            float bias = b1[n];
            #pragma unroll
            for (int mt = 0; mt < 4; ++mt) {
                f32x4 c = {0.0f, 0.0f, 0.0f, 0.0f};
                c = __builtin_amdgcn_mfma_f32_16x16x32_bf16(a[mt], b, c, 0, 0, 0);
                #pragma unroll
                for (int r = 0; r < 4; ++r) {
                    float v = c[r] + bias;
                    v = v > 0.0f ? v : 0.0f;
                    h1[mt * 16 + quad * 4 + r][n] = (bf16_t)v;
                }
            }
        }
    }
    __syncthreads();

    // phase 2: h2 = relu(h1 @ W2^T + b2). Dominant GEMM: M=64, N=512, K=512.
    {
        f32x4 acc[4][4];
        #pragma unroll
        for (int mt = 0; mt < 4; ++mt)
            #pragma unroll
            for (int nt = 0; nt < 4; ++nt)
                acc[mt][nt] = (f32x4){0.0f, 0.0f, 0.0f, 0.0f};

        for (int k0 = 0; k0 < HID; k0 += 32) {
            bf16x8 a[4];
            #pragma unroll
            for (int mt = 0; mt < 4; ++mt)
                a[mt] = *reinterpret_cast<const bf16x8*>(&h1[mt * 16 + l16][k0 + quad * 8]);
            #pragma unroll
            for (int nt = 0; nt < 4; ++nt) {
                int n = wave * 64 + nt * 16 + l16;
                bf16x8 b = *reinterpret_cast<const bf16x8*>(W2bf + n * HID + k0 + quad * 8);
                #pragma unroll
                for (int mt = 0; mt < 4; ++mt)
                    acc[mt][nt] = __builtin_amdgcn_mfma_f32_16x16x32_bf16(a[mt], b, acc[mt][nt], 0, 0, 0);
            }
        }

        #pragma unroll
        for (int nt = 0; nt < 4; ++nt) {
            int n = wave * 64 + nt * 16 + l16;
            float bias = b2[n];
            #pragma unroll
            for (int mt = 0; mt < 4; ++mt) {
                #pragma unroll
                for (int r = 0; r < 4; ++r) {
                    float v = acc[mt][nt][r] + bias;
                    v = v > 0.0f ? v : 0.0f;
                    h2[mt * 16 + quad * 4 + r][n] = (bf16_t)v;
                }
            }
        }
    }
    __syncthreads();

    // phase 3: out = h2 @ W3^T + b3 (waves 0..3, one 16-row m-tile each), then loss.
    if (wave < 4) {
        f32x4 acc3[2] = {{0.0f, 0.0f, 0.0f, 0.0f}, {0.0f, 0.0f, 0.0f, 0.0f}};
        for (int k0 = 0; k0 < HID; k0 += 32) {
            bf16x8 a = *reinterpret_cast<const bf16x8*>(&h2[wave * 16 + l16][k0 + quad * 8]);
            #pragma unroll
            for (int ot = 0; ot < 2; ++ot) {
                bf16x8 b = *reinterpret_cast<const bf16x8*>(W3bf + (ot * 16 + l16) * HID + k0 + quad * 8);
                acc3[ot] = __builtin_amdgcn_mfma_f32_16x16x32_bf16(a, b, acc3[ot], 0, 0, 0);
            }
        }

        float num = 0.0f, den = 0.0f;
        #pragma unroll
        for (int ot = 0; ot < 2; ++ot) {
            int col = ot * 16 + l16;
            if (col < OUT_DIM) {
                float bias = b3[col];
                #pragma unroll
                for (int r = 0; r < 4; ++r) {
                    long grow = row0 + wave * 16 + quad * 4 + r;
                    float pred = acc3[ot][r] + bias;
                    float g = gt[grow * OUT_DIM + col];
                    if (g > -5000.0f) {
                        // floor(x/0.5) == floor(x*2) exactly in fp32 (power-of-2 scale)
                        float w = (floorf(pred * 2.0f) == floorf(g * 2.0f)) ? 0.5f : 1.0f;
                        num += fabsf(pred * w - g * w);
                        den += 1.0f;
                    }
                }
            }
        }
        #pragma unroll
        for (int off = 32; off > 0; off >>= 1) {
            num += __shfl_down(num, off);
            den += __shfl_down(den, off);
        }
        if (lane == 0) { redbuf[wave * 2] = num; redbuf[wave * 2 + 1] = den; }
    }
    __syncthreads();
    if (tid == 0) {
        float n4 = redbuf[0] + redbuf[2] + redbuf[4] + redbuf[6];
        float d4 = redbuf[1] + redbuf[3] + redbuf[5] + redbuf[7];
        atomicAdd(accum, n4);
        atomicAdd(accum + 1, d4);
    }
}

__global__ void finalize_kernel(const float* __restrict__ accum, float* __restrict__ out) {
    if (threadIdx.x == 0) out[0] = accum[0] / accum[1];
}

extern "C" void kernel_launch(void* const* d_in, const int* in_sizes, int n_in,
                              void* d_out, int out_size, void* d_ws, size_t ws_size,
                              hipStream_t stream) {
    const float* V  = (const float*)d_in[0];
    const float* gt = (const float*)d_in[1];
    const float* W1 = (const float*)d_in[2];
    const float* b1 = (const float*)d_in[3];
    const float* W2 = (const float*)d_in[4];
    const float* b2 = (const float*)d_in[5];
    const float* W3 = (const float*)d_in[6];
    const float* b3 = (const float*)d_in[7];
    float* out = (float*)d_out;

    char* ws = (char*)d_ws;
    float* accum = (float*)ws;                                   // 2 floats (num, den)
    bf16_t* W2bf = (bf16_t*)(ws + 16);                           // 512*512*2 = 524288 B
    bf16_t* W1bf = (bf16_t*)(ws + 16 + 512 * 512 * 2);           // 512*32*2  = 32768 B
    bf16_t* W3bf = (bf16_t*)(ws + 16 + 512 * 512 * 2 + 512 * 32 * 2); // 32*512*2

    int Brows = in_sizes[0] / IN_DIM;   // 131072
    int grid = Brows / M_TILE;          // 2048

    hipMemsetAsync(accum, 0, 2 * sizeof(float), stream);
    prep_kernel<<<576, 512, 0, stream>>>(W1, W2, W3, W1bf, W2bf, W3bf);
    fused_kernel<<<grid, THREADS, 0, stream>>>(V, gt, b1, b2, b3, W1bf, W2bf, W3bf, accum);
    finalize_kernel<<<1, 64, 0, stream>>>(accum, out);
}

// Round 2
// 194.150 us; speedup vs baseline: 1.4647x; 1.4647x over previous
//
#include <hip/hip_runtime.h>
#include <hip/hip_bf16.h>

typedef __bf16 bf16_t;
typedef __bf16 bf16x8 __attribute__((ext_vector_type(8)));
typedef float f32x4 __attribute__((ext_vector_type(4)));

#define IN_DIM 21
#define HID 512
#define OUT_DIM 21
#define M_TILE 64
#define LSTRIDE 520   // 512 + 8 bf16 pad -> row stride 1040 B (2-way max bank alias on b128 reads)
#define THREADS 1024  // 16 waves -> 50% occupancy cap at 1 block/CU

// ---- prep: convert weights fp32 -> bf16 *fragment-major* layouts in ws ----
// B-fragment for 16x16x32 mfma: element (n = ntile*16 + (lane&15), k = k0 + (lane>>4)*8 + j)
// stored at frag_base + lane*8 + j  ->  wave load is contiguous 1 KB.
// W2f: [kstep(16)][ntile(32)][512]   W1f: [ntile(32)][512] (k>=21 zero)
// W3f: [kstep(16)][otile(2)][512]    (o>=21 zero)
__global__ void prep_kernel(const float* __restrict__ W1, const float* __restrict__ W2,
                            const float* __restrict__ W3,
                            bf16_t* __restrict__ W1f, bf16_t* __restrict__ W2f,
                            bf16_t* __restrict__ W3f) {
    int i = blockIdx.x * blockDim.x + threadIdx.x;
    int stride = gridDim.x * blockDim.x;
    const int NW2 = HID * HID;     // 262144
    const int NW1 = 32 * 512;      // 16384
    const int NW3 = 16 * 2 * 512;  // 16384
    for (; i < NW2 + NW1 + NW3; i += stride) {
        if (i < NW2) {
            int j = i & 7, lane = (i >> 3) & 63, ntile = (i >> 9) & 31, kstep = i >> 14;
            int n = ntile * 16 + (lane & 15);
            int k = kstep * 32 + (lane >> 4) * 8 + j;
            W2f[i] = (bf16_t)W2[n * HID + k];
        } else if (i < NW2 + NW1) {
            int t = i - NW2;
            int j = t & 7, lane = (t >> 3) & 63, ntile = t >> 9;
            int n = ntile * 16 + (lane & 15);
            int k = (lane >> 4) * 8 + j;
            W1f[t] = (k < IN_DIM) ? (bf16_t)W1[n * IN_DIM + k] : (bf16_t)0.0f;
        } else {
            int t = i - NW2 - NW1;
            int j = t & 7, lane = (t >> 3) & 63, ot = (t >> 9) & 1, kstep = t >> 10;
            int o = ot * 16 + (lane & 15);
            int k = kstep * 32 + (lane >> 4) * 8 + j;
            W3f[t] = (o < OUT_DIM) ? (bf16_t)W3[o * HID + k] : (bf16_t)0.0f;
        }
    }
}

// ---- fused MLP + loss ----
__global__ __launch_bounds__(THREADS)
void fused_kernel(const float* __restrict__ V, const float* __restrict__ gt,
                  const float* __restrict__ b1, const float* __restrict__ b2,
                  const float* __restrict__ b3,
                  const bf16_t* __restrict__ W1f, const bf16_t* __restrict__ W2f,
                  const bf16_t* __restrict__ W3f, float* __restrict__ accum) {
    __shared__ __align__(16) bf16_t vlds[M_TILE][32];
    __shared__ __align__(16) bf16_t h1[M_TILE][LSTRIDE];
    __shared__ __align__(16) bf16_t h2[M_TILE][LSTRIDE];
    __shared__ float redbuf[32];

    const int tid  = threadIdx.x;
    const int wave = tid >> 6;       // 0..15
    const int lane = tid & 63;
    const int quad = lane >> 4;
    const int l16  = lane & 15;
    const long row0 = (long)blockIdx.x * M_TILE;

    // phase 0: velocities tile -> LDS bf16, k padded to 32 with zeros
    for (int idx = tid; idx < M_TILE * 32; idx += THREADS) {
        int r = idx >> 5, c = idx & 31;
        float v = (c < IN_DIM) ? V[(row0 + r) * IN_DIM + c] : 0.0f;
        vlds[r][c] = (bf16_t)v;
    }
    __syncthreads();

    // phase 1: h1 = relu(V @ W1^T + b1). Wave covers n in [wave*32, wave*32+32).
    {
        bf16x8 a[4];
        #pragma unroll
        for (int mt = 0; mt < 4; ++mt)
            a[mt] = *reinterpret_cast<const bf16x8*>(&vlds[mt * 16 + l16][quad * 8]);
        #pragma unroll
        for (int nt = 0; nt < 2; ++nt) {
            int ntile = wave * 2 + nt;
            int n = ntile * 16 + l16;
            bf16x8 b = *reinterpret_cast<const bf16x8*>(W1f + ntile * 512 + lane * 8);
            float bias = b1[n];
            #pragma unroll
            for (int mt = 0; mt < 4; ++mt) {
                f32x4 c = {0.0f, 0.0f, 0.0f, 0.0f};
                c = __builtin_amdgcn_mfma_f32_16x16x32_bf16(a[mt], b, c, 0, 0, 0);
                #pragma unroll
                for (int r = 0; r < 4; ++r) {
                    float v = c[r] + bias;
                    v = v > 0.0f ? v : 0.0f;
                    h1[mt * 16 + quad * 4 + r][n] = (bf16_t)v;
                }
            }
        }
    }
    __syncthreads();

    // phase 2: h2 = relu(h1 @ W2^T + b2). M=64, N=512 (32/wave), K=512.
    {
        f32x4 acc[4][2];
        #pragma unroll
        for (int mt = 0; mt < 4; ++mt)
            #pragma unroll
            for (int nt = 0; nt < 2; ++nt)
                acc[mt][nt] = (f32x4){0.0f, 0.0f, 0.0f, 0.0f};

        const bf16_t* w2p0 = W2f + (wave * 2 + 0) * 512 + lane * 8;
        const bf16_t* w2p1 = W2f + (wave * 2 + 1) * 512 + lane * 8;

        for (int ks = 0; ks < 16; ++ks) {
            bf16x8 b0 = *reinterpret_cast<const bf16x8*>(w2p0 + ks * 32 * 512);
            bf16x8 b1v = *reinterpret_cast<const bf16x8*>(w2p1 + ks * 32 * 512);
            bf16x8 a[4];
            #pragma unroll
            for (int mt = 0; mt < 4; ++mt)
                a[mt] = *reinterpret_cast<const bf16x8*>(&h1[mt * 16 + l16][ks * 32 + quad * 8]);
            #pragma unroll
            for (int mt = 0; mt < 4; ++mt) {
                acc[mt][0] = __builtin_amdgcn_mfma_f32_16x16x32_bf16(a[mt], b0, acc[mt][0], 0, 0, 0);
                acc[mt][1] = __builtin_amdgcn_mfma_f32_16x16x32_bf16(a[mt], b1v, acc[mt][1], 0, 0, 0);
            }
        }

        #pragma unroll
        for (int nt = 0; nt < 2; ++nt) {
            int n = wave * 32 + nt * 16 + l16;
            float bias = b2[n];
            #pragma unroll
            for (int mt = 0; mt < 4; ++mt) {
                #pragma unroll
                for (int r = 0; r < 4; ++r) {
                    float v = acc[mt][nt][r] + bias;
                    v = v > 0.0f ? v : 0.0f;
                    h2[mt * 16 + quad * 4 + r][n] = (bf16_t)v;
                }
            }
        }
    }
    __syncthreads();

    // phase 3: out = h2 @ W3^T + b3. 8 tile-jobs (4 m-tiles x 2 o-tiles) on waves 0..7.
    if (wave < 8) {
        const int mt = wave >> 1;
        const int ot = wave & 1;
        f32x4 acc3 = {0.0f, 0.0f, 0.0f, 0.0f};
        for (int ks = 0; ks < 16; ++ks) {
            bf16x8 a = *reinterpret_cast<const bf16x8*>(&h2[mt * 16 + l16][ks * 32 + quad * 8]);
            bf16x8 b = *reinterpret_cast<const bf16x8*>(W3f + (ks * 2 + ot) * 512 + lane * 8);
            acc3 = __builtin_amdgcn_mfma_f32_16x16x32_bf16(a, b, acc3, 0, 0, 0);
        }

        float num = 0.0f, den = 0.0f;
        int col = ot * 16 + l16;
        if (col < OUT_DIM) {
            float bias = b3[col];
            #pragma unroll
            for (int r = 0; r < 4; ++r) {
                long grow = row0 + mt * 16 + quad * 4 + r;
                float pred = acc3[r] + bias;
                float g = gt[grow * OUT_DIM + col];
                if (g > -5000.0f) {
                    float w = (floorf(pred * 2.0f) == floorf(g * 2.0f)) ? 0.5f : 1.0f;
                    num += fabsf(pred * w - g * w);
                    den += 1.0f;
                }
            }
        }
        #pragma unroll
        for (int off = 32; off > 0; off >>= 1) {
            num += __shfl_down(num, off);
            den += __shfl_down(den, off);
        }
        if (lane == 0) { redbuf[wave * 2] = num; redbuf[wave * 2 + 1] = den; }
    }
    __syncthreads();
    if (tid == 0) {
        float n8 = 0.0f, d8 = 0.0f;
        #pragma unroll
        for (int w = 0; w < 8; ++w) { n8 += redbuf[w * 2]; d8 += redbuf[w * 2 + 1]; }
        atomicAdd(accum, n8);
        atomicAdd(accum + 1, d8);
    }
}

__global__ void finalize_kernel(const float* __restrict__ accum, float* __restrict__ out) {
    if (threadIdx.x == 0) out[0] = accum[0] / accum[1];
}

extern "C" void kernel_launch(void* const* d_in, const int* in_sizes, int n_in,
                              void* d_out, int out_size, void* d_ws, size_t ws_size,
                              hipStream_t stream) {
    const float* V  = (const float*)d_in[0];
    const float* gt = (const float*)d_in[1];
    const float* W1 = (const float*)d_in[2];
    const float* b1 = (const float*)d_in[3];
    const float* W2 = (const float*)d_in[4];
    const float* b2 = (const float*)d_in[5];
    const float* W3 = (const float*)d_in[6];
    const float* b3 = (const float*)d_in[7];
    float* out = (float*)d_out;

    char* ws = (char*)d_ws;
    float* accum = (float*)ws;                                       // 2 floats
    bf16_t* W2f = (bf16_t*)(ws + 16);                                // 512 KB
    bf16_t* W1f = (bf16_t*)(ws + 16 + 512 * 512 * 2);                // 32 KB
    bf16_t* W3f = (bf16_t*)(ws + 16 + 512 * 512 * 2 + 32 * 512 * 2); // 32 KB

    int Brows = in_sizes[0] / IN_DIM;   // 131072
    int grid = Brows / M_TILE;          // 2048

    hipMemsetAsync(accum, 0, 2 * sizeof(float), stream);
    prep_kernel<<<576, 512, 0, stream>>>(W1, W2, W3, W1f, W2f, W3f);
    fused_kernel<<<grid, THREADS, 0, stream>>>(V, gt, b1, b2, b3, W1f, W2f, W3f, accum);
    finalize_kernel<<<1, 64, 0, stream>>>(accum, out);
}